// Round 1
// baseline (412.259 us; speedup 1.0000x reference)
//
#include <hip/hip_runtime.h>
#include <hip/hip_bf16.h>

// Sizes (fixed by problem)
#define LQ 128
#define BZ 2
#define EE 768
#define EH 384     // E/2
#define NH 12
#define DHD 64
#define BHD 24     // B*H
#define MM 256     // L*B rows

__device__ inline float wsum(float v) {
#pragma unroll
  for (int off = 32; off; off >>= 1) v += __shfl_xor(v, off, 64);
  return v;
}

// ---------------- prep: de-interleave conv/deconv weights ----------------
// cwc[o][0:768]=conv_w[o,:,0] (prev), cwc[o][768:1536]=conv_w[o,:,1] (cur)
// dwc[o][0:768]=deconv_w[:,o,0] (cur), dwc[o][768:1536]=deconv_w[:,o,1] (prev)
__global__ void prep_weights(const float* __restrict__ conv_w,
                             const float* __restrict__ deconv_w,
                             float* __restrict__ cwc, float* __restrict__ dwc) {
  int idx = blockIdx.x * blockDim.x + threadIdx.x;
  if (idx >= EE * EE) return;
  int o = idx / EE, i = idx % EE;
  cwc[o * 1536 + i]       = conv_w[o * 1536 + 2 * i];
  cwc[o * 1536 + 768 + i] = conv_w[o * 1536 + 2 * i + 1];
  int o2 = idx % EE, i2 = idx / EE;
  dwc[o2 * 1536 + i2]       = deconv_w[i2 * 1536 + 2 * o2];
  dwc[o2 * 1536 + 768 + i2] = deconv_w[i2 * 1536 + 2 * o2 + 1];
}

// ---------------- prep: fold attn_w into q_w / k_w ----------------
__global__ void prep_reduced(const float* __restrict__ q_w, const float* __restrict__ q_b,
                             const float* __restrict__ k_w, const float* __restrict__ k_b,
                             const float* __restrict__ wv,
                             float* __restrict__ qw_red, float* __restrict__ kw_red,
                             float* __restrict__ qb_red, float* __restrict__ kb_red) {
  int idx = blockIdx.x * blockDim.x + threadIdx.x;
  if (idx < 4608) {
    int h = idx / EE, i = idx % EE;
    float s = 0.f;
    for (int d = 0; d < 64; ++d) s += q_w[(h * 64 + d) * EE + i] * wv[d];
    qw_red[idx] = s;
  } else if (idx < 9216) {
    int r = idx - 4608;
    int h = r / EE, i = r % EE;
    float s = 0.f;
    for (int d = 0; d < 64; ++d) s += k_w[(h * 64 + d) * EE + i] * wv[64 + d];
    kw_red[r] = s;
  } else if (idx < 9228) {
    int r = idx - 9216;
    int h = r % 6;
    float s = 0.f;
    if (r < 6) {
      for (int d = 0; d < 64; ++d) s += q_b[h * 64 + d] * wv[d];
      qb_red[h] = s;
    } else {
      for (int d = 0; d < 64; ++d) s += k_b[h * 64 + d] * wv[64 + d];
      kb_red[h] = s;
    }
  }
}

// ---------------- generic fp32 tiled GEMM: C[256,N] = Aeff[256,K] * Bw[N,K]^T + bias
// MODE 0: A plain (lda=K). MODE 1 (conv): K=2*K0, Aeff[r, k<K0]=A[r-2,k] (0 if r<2),
//   Aeff[r,k>=K0]=A[r,k-K0]. MODE 2 (deconv): k<K0 -> A[r,k]; k>=K0 -> A[r-2,k-K0].
template <int MODE>
__global__ __launch_bounds__(256) void gemm64(const float* __restrict__ A,
                                              const float* __restrict__ Bw,
                                              const float* __restrict__ bias,
                                              float* __restrict__ C, int N, int K) {
  __shared__ float As[16][64];
  __shared__ float Bs[16][64];
  const int n0 = blockIdx.x * 64, m0 = blockIdx.y * 64;
  const int tid = threadIdx.x;
  const int tn = tid & 15, tm = tid >> 4;
  const int lrow = tid >> 2, lkk = (tid & 3) << 2;
  const int K0 = K >> 1;
  float acc[4][4] = {};
  for (int kt = 0; kt < K; kt += 16) {
    int gk = kt + lkk;
    int r = m0 + lrow;
    float4 av;
    if (MODE == 0) {
      av = *(const float4*)(A + (size_t)r * K + gk);
    } else if (MODE == 1) {
      if (gk < K0)
        av = (r >= 2) ? *(const float4*)(A + (size_t)(r - 2) * K0 + gk) : make_float4(0, 0, 0, 0);
      else
        av = *(const float4*)(A + (size_t)r * K0 + (gk - K0));
    } else {
      if (gk < K0)
        av = *(const float4*)(A + (size_t)r * K0 + gk);
      else
        av = (r >= 2) ? *(const float4*)(A + (size_t)(r - 2) * K0 + (gk - K0)) : make_float4(0, 0, 0, 0);
    }
    float4 bv = *(const float4*)(Bw + (size_t)(n0 + lrow) * K + gk);
    As[lkk + 0][lrow] = av.x; As[lkk + 1][lrow] = av.y;
    As[lkk + 2][lrow] = av.z; As[lkk + 3][lrow] = av.w;
    Bs[lkk + 0][lrow] = bv.x; Bs[lkk + 1][lrow] = bv.y;
    Bs[lkk + 2][lrow] = bv.z; Bs[lkk + 3][lrow] = bv.w;
    __syncthreads();
#pragma unroll
    for (int k = 0; k < 16; ++k) {
      float4 a4 = *(const float4*)&As[k][tm << 2];
      float4 b4 = *(const float4*)&Bs[k][tn << 2];
      float aa[4] = {a4.x, a4.y, a4.z, a4.w};
      float bb[4] = {b4.x, b4.y, b4.z, b4.w};
#pragma unroll
      for (int i = 0; i < 4; ++i)
#pragma unroll
        for (int jj = 0; jj < 4; ++jj) acc[i][jj] += aa[i] * bb[jj];
    }
    __syncthreads();
  }
#pragma unroll
  for (int i = 0; i < 4; ++i) {
    int m = m0 + (tm << 2) + i;
    const float* bp = bias + n0 + (tn << 2);
    float4 outv = make_float4(acc[i][0] + bp[0], acc[i][1] + bp[1],
                              acc[i][2] + bp[2], acc[i][3] + bp[3]);
    *(float4*)(C + (size_t)m * N + n0 + (tn << 2)) = outv;
  }
}

// ---------------- score-table dot products ----------------
// A[m,x] (3072), Bk[m,l] (3072), Ew[t,b,cb] (3072). One wave per output.
__global__ void dots_kernel(const float* __restrict__ nq, const float* __restrict__ e_buf,
                            const float* __restrict__ entity,
                            const float* __restrict__ qw_red, const float* __restrict__ kw_red,
                            const float* __restrict__ qb_red, const float* __restrict__ kb_red,
                            const float* __restrict__ wv,
                            float* __restrict__ Abuf, float* __restrict__ Bkbuf,
                            float* __restrict__ Ewbuf) {
  int w = blockIdx.x * 4 + (threadIdx.x >> 6);
  int lane = threadIdx.x & 63;
  if (w < 3072) {
    int m = w >> 7, x = w & 127;
    int b = m / 12, h = m % 12;
    float s;
    if (h < 6) {
      const float* a = nq + (x * 2 + b) * EE;
      const float* ww = qw_red + h * EE;
      float p = 0.f;
#pragma unroll
      for (int it = 0; it < 12; ++it) p += a[lane + it * 64] * ww[lane + it * 64];
      s = wsum(p) + qb_red[h];
    } else {
      s = wsum(e_buf[(x * 2 + b) * EH + (h - 6) * 64 + lane] * wv[lane]);
    }
    if (lane == 0) Abuf[w] = s;
  } else if (w < 6144) {
    int r = w - 3072;
    int m = r >> 7, l = r & 127;
    int b = m / 12, h = m % 12;
    float s;
    if (h < 6) {
      const float* a = nq + (l * 2 + b) * EE;
      const float* ww = kw_red + h * EE;
      float p = 0.f;
#pragma unroll
      for (int it = 0; it < 12; ++it) p += a[lane + it * 64] * ww[lane + it * 64];
      s = wsum(p) + kb_red[h];
    } else {
      s = wsum(e_buf[(l * 2 + b) * EH + (h - 6) * 64 + lane] * wv[64 + lane]);
    }
    if (lane == 0) Bkbuf[r] = s;
  } else if (w < 9216) {
    int r = w - 6144;
    int t = r / 24, q = r % 24, b = q / 12, cb = q % 12;
    float s = wsum(entity[(t * 2 + b) * EE + cb * 64 + lane] * wv[128 + lane]);
    if (lane == 0) Ewbuf[r] = s;
  }
}

// ---------------- scores + leaky_relu + softmax + PV, one block per (bh, i2) ----------------
__global__ __launch_bounds__(128) void attn_kernel(
    const float* __restrict__ Abuf, const float* __restrict__ Bkbuf,
    const float* __restrict__ Ewbuf, const float* __restrict__ attn_b,
    const float* __restrict__ v_buf, const float* __restrict__ e_buf,
    float* __restrict__ a_out) {
  int bh = blockIdx.x >> 7, i2 = blockIdx.x & 127;
  int tid = threadIdx.x;
  int j = tid;
  int G = bh * 16384 + i2 * 128 + j;
  int mq = G % 24, xq = (G / 24) >> 7;
  int mk = (bh * 128 + i2) % 24;
  int cb = G % 12, gb = G / 12;
  int be = gb & 1, ij = gb >> 1, ie = ij >> 7, je = ij & 127;
  float s = Abuf[mq * 128 + xq] + Bkbuf[mk * 128 + j] + Ewbuf[ie * 24 + be * 12 + cb] -
            Ewbuf[je * 24 + be * 12 + cb] + attn_b[0];
  s = s >= 0.f ? s : 0.01f * s;  // leaky_relu

  __shared__ float ps[128];
  __shared__ float red[4];
  int lane = tid & 63, wid = tid >> 6;
  float mv = s;
#pragma unroll
  for (int off = 32; off; off >>= 1) mv = fmaxf(mv, __shfl_xor(mv, off, 64));
  if (lane == 0) red[wid] = mv;
  __syncthreads();
  float gmax = fmaxf(red[0], red[1]);
  float ex = expf(s - gmax);
  float sv = wsum(ex);
  if (lane == 0) red[2 + wid] = sv;
  __syncthreads();
  float gsum = red[2] + red[3];
  ps[tid] = ex / gsum;
  __syncthreads();

  // PV: attn[bh,i2,d] = sum_j p[j] * ve[bh,j,d]
  int d = tid & 63, half = tid >> 6;
  int b = bh / 12, h = bh % 12;
  const float* src = (h < 6) ? (v_buf + h * 64) : (e_buf + (h - 6) * 64);
  float acc = 0.f;
#pragma unroll 4
  for (int jj = 0; jj < 64; ++jj) {
    int jx = half * 64 + jj;
    acc += ps[jx] * src[(jx * 2 + b) * EH + d];
  }
  __shared__ float pv[2][64];
  pv[half][d] = acc;
  __syncthreads();
  if (tid < 64) {
    a_out[(i2 * 2 + b) * EE + h * 64 + tid] = pv[0][tid] + pv[1][tid];
  }
}

extern "C" void kernel_launch(void* const* d_in, const int* in_sizes, int n_in,
                              void* d_out, int out_size, void* d_ws, size_t ws_size,
                              hipStream_t stream) {
  const float* query    = (const float*)d_in[0];
  const float* entity   = (const float*)d_in[1];
  const float* conv_w   = (const float*)d_in[2];
  const float* conv_b   = (const float*)d_in[3];
  const float* q_w      = (const float*)d_in[4];
  const float* q_b      = (const float*)d_in[5];
  const float* k_w      = (const float*)d_in[6];
  const float* k_b      = (const float*)d_in[7];
  const float* v_w      = (const float*)d_in[8];
  const float* v_b      = (const float*)d_in[9];
  const float* e_w      = (const float*)d_in[10];
  const float* e_b      = (const float*)d_in[11];
  const float* attn_w   = (const float*)d_in[12];
  const float* attn_b   = (const float*)d_in[13];
  const float* deconv_w = (const float*)d_in[14];
  const float* deconv_b = (const float*)d_in[15];
  const float* out_w    = (const float*)d_in[16];
  const float* out_b    = (const float*)d_in[17];

  float* ws    = (float*)d_ws;
  float* cwc   = ws;                  // 768*1536
  float* dwc   = cwc + 1179648;       // 768*1536
  float* nq    = dwc + 1179648;       // 256*768
  float* e_buf = nq + 196608;         // 256*384
  float* v_buf = e_buf + 98304;       // 256*384
  float* qw_red = v_buf + 98304;      // 6*768
  float* kw_red = qw_red + 4608;      // 6*768
  float* qb_red = kw_red + 4608;      // 16
  float* kb_red = qb_red + 16;        // 16
  float* Abuf  = kb_red + 16;         // 3072
  float* Bkbuf = Abuf + 3072;         // 3072
  float* Ewbuf = Bkbuf + 3072;        // 3072
  float* a_buf = Ewbuf + 3072;        // 256*768
  float* y_buf = a_buf + 196608;      // 256*768
  // total ~12.1 MiB of ws

  prep_weights<<<(EE * EE) / 256, 256, 0, stream>>>(conv_w, deconv_w, cwc, dwc);
  prep_reduced<<<(9228 + 255) / 256, 256, 0, stream>>>(q_w, q_b, k_w, k_b, attn_w,
                                                       qw_red, kw_red, qb_red, kb_red);
  // nq = conv1d(query)
  gemm64<1><<<dim3(12, 4), 256, 0, stream>>>(query, cwc, conv_b, nq, 768, 1536);
  // e = entity @ e_w^T + e_b ; v = nq @ v_w^T + v_b
  gemm64<0><<<dim3(6, 4), 256, 0, stream>>>(entity, e_w, e_b, e_buf, 384, 768);
  gemm64<0><<<dim3(6, 4), 256, 0, stream>>>(nq, v_w, v_b, v_buf, 384, 768);
  // score tables
  dots_kernel<<<2304, 256, 0, stream>>>(nq, e_buf, entity, qw_red, kw_red, qb_red,
                                        kb_red, attn_w, Abuf, Bkbuf, Ewbuf);
  // scores + softmax + PV -> a (L,B,E)
  attn_kernel<<<BHD * LQ, 128, 0, stream>>>(Abuf, Bkbuf, Ewbuf, attn_b, v_buf, e_buf, a_buf);
  // y = deconv(a)
  gemm64<2><<<dim3(12, 4), 256, 0, stream>>>(a_buf, dwc, deconv_b, y_buf, 768, 1536);
  // out = y @ out_w^T + out_b
  gemm64<0><<<dim3(12, 4), 256, 0, stream>>>(y_buf, out_w, out_b, (float*)d_out, 768, 768);
}

// Round 2
// 212.014 us; speedup vs baseline: 1.9445x; 1.9445x over previous
//
#include <hip/hip_runtime.h>
#include <hip/hip_bf16.h>

// Sizes (fixed by problem)
#define LQ 128
#define BZ 2
#define EE 768
#define EH 384     // E/2
#define NH 12
#define DHD 64
#define BHD 24     // B*H
#define MM 256     // L*B rows

__device__ inline float wsum(float v) {
#pragma unroll
  for (int off = 32; off; off >>= 1) v += __shfl_xor(v, off, 64);
  return v;
}

// ---------------- fused prep: weight de-interleave + attn_w folding + bias init ----
// region A: de-interleave conv/deconv weights
//   cwc[o][0:768]=conv_w[o,:,0] (prev), cwc[o][768:1536]=conv_w[o,:,1] (cur)
//   dwc[o][0:768]=deconv_w[:,o,0] (cur), dwc[o][768:1536]=deconv_w[:,o,1] (prev)
// region B: fold attn_w into q_w/k_w -> qw_red/kw_red (+ reduced biases)
// region C: write bias rows into nq, e_buf, v_buf, y_buf, dout (GEMMs accumulate)
__global__ void prep_all(const float* __restrict__ conv_w, const float* __restrict__ deconv_w,
                         const float* __restrict__ q_w, const float* __restrict__ q_b,
                         const float* __restrict__ k_w, const float* __restrict__ k_b,
                         const float* __restrict__ wv,
                         const float* __restrict__ conv_b, const float* __restrict__ e_b,
                         const float* __restrict__ v_b, const float* __restrict__ deconv_b,
                         const float* __restrict__ out_b,
                         float* __restrict__ cwc, float* __restrict__ dwc,
                         float* __restrict__ qw_red, float* __restrict__ kw_red,
                         float* __restrict__ qb_red, float* __restrict__ kb_red,
                         float* __restrict__ nq, float* __restrict__ e_buf,
                         float* __restrict__ v_buf, float* __restrict__ y_buf,
                         float* __restrict__ dout) {
  int idx = blockIdx.x * blockDim.x + threadIdx.x;
  if (idx < 589824) {
    int o = idx / EE, i = idx % EE;
    cwc[o * 1536 + i]       = conv_w[o * 1536 + 2 * i];
    cwc[o * 1536 + 768 + i] = conv_w[o * 1536 + 2 * i + 1];
    int o2 = idx % EE, i2 = idx / EE;
    dwc[o2 * 1536 + i2]       = deconv_w[i2 * 1536 + 2 * o2];
    dwc[o2 * 1536 + 768 + i2] = deconv_w[i2 * 1536 + 2 * o2 + 1];
  } else if (idx < 599052) {
    int r = idx - 589824;
    if (r < 4608) {
      int h = r / EE, i = r % EE;
      float s = 0.f;
      for (int d = 0; d < 64; ++d) s += q_w[(h * 64 + d) * EE + i] * wv[d];
      qw_red[r] = s;
    } else if (r < 9216) {
      int r2 = r - 4608;
      int h = r2 / EE, i = r2 % EE;
      float s = 0.f;
      for (int d = 0; d < 64; ++d) s += k_w[(h * 64 + d) * EE + i] * wv[64 + d];
      kw_red[r2] = s;
    } else {
      int r2 = r - 9216;
      int h = r2 % 6;
      float s = 0.f;
      if (r2 < 6) {
        for (int d = 0; d < 64; ++d) s += q_b[h * 64 + d] * wv[d];
        qb_red[h] = s;
      } else {
        for (int d = 0; d < 64; ++d) s += k_b[h * 64 + d] * wv[64 + d];
        kb_red[h] = s;
      }
    }
  } else if (idx < 1385484) {
    int r = idx - 599052;
    int row = r / 3072, c = r % 3072;
    if (c < 768)       nq[row * 768 + c] = conv_b[c];
    else if (c < 1152) e_buf[row * 384 + (c - 768)] = e_b[c - 768];
    else if (c < 1536) v_buf[row * 384 + (c - 1152)] = v_b[c - 1152];
    else if (c < 2304) y_buf[row * 768 + (c - 1536)] = deconv_b[c - 1536];
    else               dout[row * 768 + (c - 2304)] = out_b[c - 2304];
  }
}

// ---------------- split-K fp32 GEMM body: C[256,N] += Aeff[256,Kchunk] * Bw[N,K]^T
// 32(M) x 64(N) tile, 256 threads, BK=32, register double-buffer prefetch,
// atomic accumulation into pre-biased C.
// MODE 0: A plain (lda=K). MODE 1 (conv, K=1536): k<768 -> A[r-2,k] (0 if r<2),
//   k>=768 -> A[r,k-768]. MODE 2 (deconv): k<768 -> A[r,k]; k>=768 -> A[r-2,k-768].
template <int MODE>
__device__ __forceinline__ void gemm_body(const float* __restrict__ A,
                                          const float* __restrict__ Bw,
                                          float* __restrict__ C,
                                          int N, int K, int kbase, int kChunk) {
  __shared__ float As[32][36];
  __shared__ float Bs[32][68];
  const int n0 = blockIdx.x * 64, m0 = blockIdx.y * 32;
  const int tid = threadIdx.x;
  const int ar = tid >> 3, ak4 = (tid & 7) << 2;   // A stage: 32 rows x 32 k
  const int br = tid >> 2, bk4 = (tid & 3) << 2;   // B stage: 64 rows x 32 k (x2)
  const int tn = tid & 15, tm = tid >> 4;          // compute: 2m x 4n per thread
  const int K0 = 768;

  auto ldA = [&](int r, int gk) -> float4 {
    if (MODE == 0) return *(const float4*)(A + (size_t)r * K + gk);
    if (MODE == 1) {
      if (gk < K0)
        return (r >= 2) ? *(const float4*)(A + (size_t)(r - 2) * K0 + gk)
                        : make_float4(0.f, 0.f, 0.f, 0.f);
      return *(const float4*)(A + (size_t)r * K0 + (gk - K0));
    }
    if (gk < K0) return *(const float4*)(A + (size_t)r * K0 + gk);
    return (r >= 2) ? *(const float4*)(A + (size_t)(r - 2) * K0 + (gk - K0))
                    : make_float4(0.f, 0.f, 0.f, 0.f);
  };

  int kt = kbase;
  float4 pa  = ldA(m0 + ar, kt + ak4);
  float4 pb0 = *(const float4*)(Bw + (size_t)(n0 + br) * K + kt + bk4);
  float4 pb1 = *(const float4*)(Bw + (size_t)(n0 + br) * K + kt + bk4 + 16);

  float acc[2][4] = {};
  const int kend = kbase + kChunk;
  for (; kt < kend; kt += 32) {
    As[ak4 + 0][ar] = pa.x; As[ak4 + 1][ar] = pa.y;
    As[ak4 + 2][ar] = pa.z; As[ak4 + 3][ar] = pa.w;
    Bs[bk4 + 0][br] = pb0.x; Bs[bk4 + 1][br] = pb0.y;
    Bs[bk4 + 2][br] = pb0.z; Bs[bk4 + 3][br] = pb0.w;
    Bs[bk4 + 16][br] = pb1.x; Bs[bk4 + 17][br] = pb1.y;
    Bs[bk4 + 18][br] = pb1.z; Bs[bk4 + 19][br] = pb1.w;
    __syncthreads();
    int nk = kt + 32;
    if (nk < kend) {
      pa  = ldA(m0 + ar, nk + ak4);
      pb0 = *(const float4*)(Bw + (size_t)(n0 + br) * K + nk + bk4);
      pb1 = *(const float4*)(Bw + (size_t)(n0 + br) * K + nk + bk4 + 16);
    }
#pragma unroll
    for (int k = 0; k < 32; ++k) {
      float2 a2 = *(const float2*)&As[k][tm << 1];
      float4 b4 = *(const float4*)&Bs[k][tn << 2];
      float aa[2] = {a2.x, a2.y};
      float bb[4] = {b4.x, b4.y, b4.z, b4.w};
#pragma unroll
      for (int i = 0; i < 2; ++i)
#pragma unroll
        for (int j = 0; j < 4; ++j) acc[i][j] += aa[i] * bb[j];
    }
    __syncthreads();
  }
#pragma unroll
  for (int i = 0; i < 2; ++i) {
    int m = m0 + (tm << 1) + i;
#pragma unroll
    for (int j = 0; j < 4; ++j) {
      unsafeAtomicAdd(&C[(size_t)m * N + n0 + (tn << 2) + j], acc[i][j]);
    }
  }
}

template <int MODE>
__global__ __launch_bounds__(256) void gemm_sk(const float* __restrict__ A,
                                               const float* __restrict__ Bw,
                                               float* __restrict__ C, int N, int K,
                                               int kChunk) {
  gemm_body<MODE>(A, Bw, C, N, K, blockIdx.z * kChunk, kChunk);
}

// e and v projections in one launch: grid.z in [0,16); z<8 -> e, z>=8 -> v
__global__ __launch_bounds__(256) void gemm_ev(const float* __restrict__ entity,
                                               const float* __restrict__ e_w,
                                               const float* __restrict__ nq,
                                               const float* __restrict__ v_w,
                                               float* __restrict__ e_buf,
                                               float* __restrict__ v_buf) {
  int z = blockIdx.z;
  if (z < 8) {
    gemm_body<0>(entity, e_w, e_buf, 384, 768, z * 96, 96);
  } else {
    gemm_body<0>(nq, v_w, v_buf, 384, 768, (z - 8) * 96, 96);
  }
}

// ---------------- score-table dot products ----------------
// A[m,x] (3072), Bk[m,l] (3072), Ew[t,b,cb] (3072). One wave per output.
__global__ void dots_kernel(const float* __restrict__ nq, const float* __restrict__ e_buf,
                            const float* __restrict__ entity,
                            const float* __restrict__ qw_red, const float* __restrict__ kw_red,
                            const float* __restrict__ qb_red, const float* __restrict__ kb_red,
                            const float* __restrict__ wv,
                            float* __restrict__ Abuf, float* __restrict__ Bkbuf,
                            float* __restrict__ Ewbuf) {
  int w = blockIdx.x * 4 + (threadIdx.x >> 6);
  int lane = threadIdx.x & 63;
  if (w < 3072) {
    int m = w >> 7, x = w & 127;
    int b = m / 12, h = m % 12;
    float s;
    if (h < 6) {
      const float* a = nq + (x * 2 + b) * EE;
      const float* ww = qw_red + h * EE;
      float p = 0.f;
#pragma unroll
      for (int it = 0; it < 12; ++it) p += a[lane + it * 64] * ww[lane + it * 64];
      s = wsum(p) + qb_red[h];
    } else {
      s = wsum(e_buf[(x * 2 + b) * EH + (h - 6) * 64 + lane] * wv[lane]);
    }
    if (lane == 0) Abuf[w] = s;
  } else if (w < 6144) {
    int r = w - 3072;
    int m = r >> 7, l = r & 127;
    int b = m / 12, h = m % 12;
    float s;
    if (h < 6) {
      const float* a = nq + (l * 2 + b) * EE;
      const float* ww = kw_red + h * EE;
      float p = 0.f;
#pragma unroll
      for (int it = 0; it < 12; ++it) p += a[lane + it * 64] * ww[lane + it * 64];
      s = wsum(p) + kb_red[h];
    } else {
      s = wsum(e_buf[(l * 2 + b) * EH + (h - 6) * 64 + lane] * wv[64 + lane]);
    }
    if (lane == 0) Bkbuf[r] = s;
  } else if (w < 9216) {
    int r = w - 6144;
    int t = r / 24, q = r % 24, b = q / 12, cb = q % 12;
    float s = wsum(entity[(t * 2 + b) * EE + cb * 64 + lane] * wv[128 + lane]);
    if (lane == 0) Ewbuf[r] = s;
  }
}

// ---------------- scores + leaky_relu + softmax + PV, one block per (bh, i2) ----------------
__global__ __launch_bounds__(128) void attn_kernel(
    const float* __restrict__ Abuf, const float* __restrict__ Bkbuf,
    const float* __restrict__ Ewbuf, const float* __restrict__ attn_b,
    const float* __restrict__ v_buf, const float* __restrict__ e_buf,
    float* __restrict__ a_out) {
  int bh = blockIdx.x >> 7, i2 = blockIdx.x & 127;
  int tid = threadIdx.x;
  int j = tid;
  int G = bh * 16384 + i2 * 128 + j;
  int mq = G % 24, xq = (G / 24) >> 7;
  int mk = (bh * 128 + i2) % 24;
  int cb = G % 12, gb = G / 12;
  int be = gb & 1, ij = gb >> 1, ie = ij >> 7, je = ij & 127;
  float s = Abuf[mq * 128 + xq] + Bkbuf[mk * 128 + j] + Ewbuf[ie * 24 + be * 12 + cb] -
            Ewbuf[je * 24 + be * 12 + cb] + attn_b[0];
  s = s >= 0.f ? s : 0.01f * s;  // leaky_relu

  __shared__ float ps[128];
  __shared__ float red[4];
  int lane = tid & 63, wid = tid >> 6;
  float mv = s;
#pragma unroll
  for (int off = 32; off; off >>= 1) mv = fmaxf(mv, __shfl_xor(mv, off, 64));
  if (lane == 0) red[wid] = mv;
  __syncthreads();
  float gmax = fmaxf(red[0], red[1]);
  float ex = expf(s - gmax);
  float sv = wsum(ex);
  if (lane == 0) red[2 + wid] = sv;
  __syncthreads();
  float gsum = red[2] + red[3];
  ps[tid] = ex / gsum;
  __syncthreads();

  // PV: attn[bh,i2,d] = sum_j p[j] * ve[bh,j,d]
  int d = tid & 63, half = tid >> 6;
  int b = bh / 12, h = bh % 12;
  const float* src = (h < 6) ? (v_buf + h * 64) : (e_buf + (h - 6) * 64);
  float acc = 0.f;
#pragma unroll 4
  for (int jj = 0; jj < 64; ++jj) {
    int jx = half * 64 + jj;
    acc += ps[jx] * src[(jx * 2 + b) * EH + d];
  }
  __shared__ float pv[2][64];
  pv[half][d] = acc;
  __syncthreads();
  if (tid < 64) {
    a_out[(i2 * 2 + b) * EE + h * 64 + tid] = pv[0][tid] + pv[1][tid];
  }
}

extern "C" void kernel_launch(void* const* d_in, const int* in_sizes, int n_in,
                              void* d_out, int out_size, void* d_ws, size_t ws_size,
                              hipStream_t stream) {
  const float* query    = (const float*)d_in[0];
  const float* entity   = (const float*)d_in[1];
  const float* conv_w   = (const float*)d_in[2];
  const float* conv_b   = (const float*)d_in[3];
  const float* q_w      = (const float*)d_in[4];
  const float* q_b      = (const float*)d_in[5];
  const float* k_w      = (const float*)d_in[6];
  const float* k_b      = (const float*)d_in[7];
  const float* v_w      = (const float*)d_in[8];
  const float* v_b      = (const float*)d_in[9];
  const float* e_w      = (const float*)d_in[10];
  const float* e_b      = (const float*)d_in[11];
  const float* attn_w   = (const float*)d_in[12];
  const float* attn_b   = (const float*)d_in[13];
  const float* deconv_w = (const float*)d_in[14];
  const float* deconv_b = (const float*)d_in[15];
  const float* out_w    = (const float*)d_in[16];
  const float* out_b    = (const float*)d_in[17];

  float* ws    = (float*)d_ws;
  float* cwc   = ws;                  // 768*1536
  float* dwc   = cwc + 1179648;       // 768*1536
  float* nq    = dwc + 1179648;       // 256*768
  float* e_buf = nq + 196608;         // 256*384
  float* v_buf = e_buf + 98304;       // 256*384
  float* qw_red = v_buf + 98304;      // 6*768
  float* kw_red = qw_red + 4608;      // 6*768
  float* qb_red = kw_red + 4608;      // 16
  float* kb_red = qb_red + 16;        // 16
  float* Abuf  = kb_red + 16;         // 3072
  float* Bkbuf = Abuf + 3072;         // 3072
  float* Ewbuf = Bkbuf + 3072;        // 3072
  float* a_buf = Ewbuf + 3072;        // 256*768
  float* y_buf = a_buf + 196608;      // 256*768

  float* dout = (float*)d_out;

  // 1. fused prep: weight layouts + folded attn_w + bias init of all C buffers
  prep_all<<<5413, 256, 0, stream>>>(conv_w, deconv_w, q_w, q_b, k_w, k_b, attn_w,
                                     conv_b, e_b, v_b, deconv_b, out_b,
                                     cwc, dwc, qw_red, kw_red, qb_red, kb_red,
                                     nq, e_buf, v_buf, y_buf, dout);
  // 2. nq += conv1d(query): M=256 N=768 K=1536, splitk 4
  gemm_sk<1><<<dim3(12, 8, 4), 256, 0, stream>>>(query, cwc, nq, 768, 1536, 384);
  // 3. e += entity@e_w^T ; v += nq@v_w^T (one launch, splitk 8 each)
  gemm_ev<<<dim3(6, 8, 16), 256, 0, stream>>>(entity, e_w, nq, v_w, e_buf, v_buf);
  // 4. score tables
  dots_kernel<<<2304, 256, 0, stream>>>(nq, e_buf, entity, qw_red, kw_red, qb_red,
                                        kb_red, attn_w, Abuf, Bkbuf, Ewbuf);
  // 5. scores + softmax + PV -> a (L,B,E)
  attn_kernel<<<BHD * LQ, 128, 0, stream>>>(Abuf, Bkbuf, Ewbuf, attn_b, v_buf, e_buf, a_buf);
  // 6. y += deconv(a): splitk 4
  gemm_sk<2><<<dim3(12, 8, 4), 256, 0, stream>>>(a_buf, dwc, y_buf, 768, 1536, 384);
  // 7. out += y@out_w^T: splitk 4
  gemm_sk<0><<<dim3(12, 8, 4), 256, 0, stream>>>(y_buf, out_w, dout, 768, 768, 192);
}

// Round 4
// 209.545 us; speedup vs baseline: 1.9674x; 1.0118x over previous
//
#include <hip/hip_runtime.h>
#include <hip/hip_bf16.h>

#define LQ 128
#define BZ 2
#define EE 768
#define EH 384
#define NH 12
#define DHD 64
#define BHD 24
#define MM 256

__device__ inline float wsum(float v) {
#pragma unroll
  for (int off = 32; off; off >>= 1) v += __shfl_xor(v, off, 64);
  return v;
}

// =============== conv-like GEMM core (direct interleaved weights) ===============
// Computes C[m,n] = sum_i ( a_cur[m,i]*Wc[n,i] + a_prev[m-2,i]*Wp[n,i] ) over
// i in [kbase, kbase+384), writing a PARTIAL (no bias) into C (256x768).
// TAPMODE 0 (conv):    W layout (n,i,tap) row-major interleaved; cur pairs tap1, prev tap0.
// TAPMODE 1 (deconv):  W layout (i,n,tap) k-major interleaved;   cur pairs tap0, prev tap1.
template <int TAPMODE>
__device__ __forceinline__ void conv_core(const float* __restrict__ A,
                                          const float* __restrict__ W,
                                          float* __restrict__ C,
                                          int m0, int n0, int kbase, float* smem) {
  float* As  = smem;           // [32 k][36] rows 0..33 = global m0-2..m0+31
  float* Bs0 = smem + 1152;    // [32 i][68] tap0
  float* Bs1 = Bs0 + 2176;     // [32 i][68] tap1
  const int tid = threadIdx.x;
  const int ar = tid >> 3, ak4 = (tid & 7) << 2;
  const int gmA = m0 - 2 + ar;
  const bool extra = (tid < 16);
  const int ar2 = 32 + (tid >> 3);        // valid when extra
  const int gmA2 = m0 + 30 + (tid >> 3);  // = m0-2+ar2
  const int tn = tid & 15, tm = tid >> 4;

  // B addressing
  const int bn = tid >> 2, ig = tid & 3;  // TAPMODE 0
  const int il = tid >> 3, ng = tid & 7;  // TAPMODE 1

  float4 pa, pa2, pb[4];
  auto ld = [&](int kt) {
    int gi = kbase + kt;
    pa = (gmA >= 0) ? *(const float4*)(A + (size_t)gmA * 768 + gi + ak4)
                    : make_float4(0.f, 0.f, 0.f, 0.f);
    if (extra) pa2 = *(const float4*)(A + (size_t)gmA2 * 768 + gi + ak4);
    if (TAPMODE == 0) {
      const float* wrow = W + (size_t)(n0 + bn) * 1536 + 2 * (gi + ig * 8);
#pragma unroll
      for (int c = 0; c < 4; ++c) pb[c] = *(const float4*)(wrow + 4 * c);
    } else {
      const float* wrow = W + (size_t)(gi + il) * 1536 + 2 * (n0 + ng * 8);
#pragma unroll
      for (int c = 0; c < 4; ++c) pb[c] = *(const float4*)(wrow + 4 * c);
    }
  };

  ld(0);
  float acc[2][4] = {};
  for (int kt = 0; kt < 384; kt += 32) {
#pragma unroll
    for (int c = 0; c < 4; ++c) {
      float v = (c == 0) ? pa.x : (c == 1) ? pa.y : (c == 2) ? pa.z : pa.w;
      As[(ak4 + c) * 36 + ar] = v;
    }
    if (extra) {
#pragma unroll
      for (int c = 0; c < 4; ++c) {
        float v = (c == 0) ? pa2.x : (c == 1) ? pa2.y : (c == 2) ? pa2.z : pa2.w;
        As[(ak4 + c) * 36 + ar2] = v;
      }
    }
    if (TAPMODE == 0) {
#pragma unroll
      for (int c = 0; c < 4; ++c) {
        int i_l = ig * 8 + 2 * c;
        Bs0[i_l * 68 + bn] = pb[c].x; Bs1[i_l * 68 + bn] = pb[c].y;
        Bs0[(i_l + 1) * 68 + bn] = pb[c].z; Bs1[(i_l + 1) * 68 + bn] = pb[c].w;
      }
    } else {
#pragma unroll
      for (int c = 0; c < 4; ++c) {
        int n_l = ng * 8 + 2 * c;
        Bs0[il * 68 + n_l] = pb[c].x; Bs1[il * 68 + n_l] = pb[c].y;
        Bs0[il * 68 + n_l + 1] = pb[c].z; Bs1[il * 68 + n_l + 1] = pb[c].w;
      }
    }
    __syncthreads();
    if (kt + 32 < 384) ld(kt + 32);
#pragma unroll
    for (int i = 0; i < 32; ++i) {
      float4 b0 = *(const float4*)(Bs0 + i * 68 + (tn << 2));
      float4 b1 = *(const float4*)(Bs1 + i * 68 + (tn << 2));
      float ap0 = As[i * 36 + (tm << 1)];
      float ap1 = As[i * 36 + (tm << 1) + 1];
      float ac0 = As[i * 36 + (tm << 1) + 2];
      float ac1 = As[i * 36 + (tm << 1) + 3];
      float bc[4] = {b0.x, b0.y, b0.z, b0.w};
      float bp[4] = {b1.x, b1.y, b1.z, b1.w};
#pragma unroll
      for (int jj = 0; jj < 4; ++jj) {
        if (TAPMODE == 0) {  // cur*tap1 + prev*tap0
          acc[0][jj] += ac0 * bp[jj] + ap0 * bc[jj];
          acc[1][jj] += ac1 * bp[jj] + ap1 * bc[jj];
        } else {             // cur*tap0 + prev*tap1
          acc[0][jj] += ac0 * bc[jj] + ap0 * bp[jj];
          acc[1][jj] += ac1 * bc[jj] + ap1 * bp[jj];
        }
      }
    }
    __syncthreads();
  }
#pragma unroll
  for (int j = 0; j < 2; ++j) {
    int m = m0 + (tm << 1) + j;
    float4 o = make_float4(acc[j][0], acc[j][1], acc[j][2], acc[j][3]);
    *(float4*)(C + (size_t)m * 768 + n0 + (tn << 2)) = o;
  }
}

// =============== plain GEMM core: C[256,N] = Aeff[256,768-chunk] * Bw[N,768]^T ===============
// SUM2: Aeff = A + A2 + ab (row-broadcast). ATOMIC: atomadd into C with optional bias.
template <bool SUM2, bool ATOMIC>
__device__ __forceinline__ void gemm_plain(const float* __restrict__ A,
                                           const float* __restrict__ A2,
                                           const float* __restrict__ ab,
                                           const float* __restrict__ Bw,
                                           const float* __restrict__ bias,
                                           float* __restrict__ C, int N,
                                           int m0, int n0, int kbase, int kchunk,
                                           float* smem) {
  float* As = smem;          // [32][36]
  float* Bs = smem + 1152;   // [32][68]
  const int tid = threadIdx.x;
  const int ar = tid >> 3, ak4 = (tid & 7) << 2;
  const int br = tid >> 2, bk4 = (tid & 3) << 2;
  const int tn = tid & 15, tm = tid >> 4;
  const float* Arow = A + (size_t)(m0 + ar) * 768;
  const float* A2row = A2 ? A2 + (size_t)(m0 + ar) * 768 : nullptr;
  const float* Brow = Bw + (size_t)(n0 + br) * 768;
  float4 pa, pb0, pb1;
  auto ld = [&](int kt) {
    int gi = kbase + kt;
    pa = *(const float4*)(Arow + gi + ak4);
    if (SUM2) {
      float4 t2 = *(const float4*)(A2row + gi + ak4);
      float4 t3 = *(const float4*)(ab + gi + ak4);
      pa.x += t2.x + t3.x; pa.y += t2.y + t3.y;
      pa.z += t2.z + t3.z; pa.w += t2.w + t3.w;
    }
    pb0 = *(const float4*)(Brow + gi + bk4);
    pb1 = *(const float4*)(Brow + gi + bk4 + 16);
  };
  ld(0);
  float acc[2][4] = {};
  for (int kt = 0; kt < kchunk; kt += 32) {
    As[(ak4 + 0) * 36 + ar] = pa.x; As[(ak4 + 1) * 36 + ar] = pa.y;
    As[(ak4 + 2) * 36 + ar] = pa.z; As[(ak4 + 3) * 36 + ar] = pa.w;
    Bs[(bk4 + 0) * 68 + br] = pb0.x; Bs[(bk4 + 1) * 68 + br] = pb0.y;
    Bs[(bk4 + 2) * 68 + br] = pb0.z; Bs[(bk4 + 3) * 68 + br] = pb0.w;
    Bs[(bk4 + 16) * 68 + br] = pb1.x; Bs[(bk4 + 17) * 68 + br] = pb1.y;
    Bs[(bk4 + 18) * 68 + br] = pb1.z; Bs[(bk4 + 19) * 68 + br] = pb1.w;
    __syncthreads();
    if (kt + 32 < kchunk) ld(kt + 32);
#pragma unroll
    for (int k = 0; k < 32; ++k) {
      float2 a2 = *(const float2*)(As + k * 36 + (tm << 1));
      float4 b4 = *(const float4*)(Bs + k * 68 + (tn << 2));
      float aa[2] = {a2.x, a2.y};
      float bb[4] = {b4.x, b4.y, b4.z, b4.w};
#pragma unroll
      for (int i = 0; i < 2; ++i)
#pragma unroll
        for (int j = 0; j < 4; ++j) acc[i][j] += aa[i] * bb[j];
    }
    __syncthreads();
  }
#pragma unroll
  for (int i = 0; i < 2; ++i) {
    int m = m0 + (tm << 1) + i;
#pragma unroll
    for (int j = 0; j < 4; ++j) {
      int n = n0 + (tn << 2) + j;
      if (ATOMIC) {
        float bv = bias ? bias[n] : 0.f;
        unsafeAtomicAdd(&C[(size_t)m * N + n], acc[i][j] + bv);
      } else {
        C[(size_t)m * N + n] = acc[i][j] + bias[n];
      }
    }
  }
}

// =============== K1: conv(split2) | e-gemm | attn_w fold | Ew dots ===============
__global__ __launch_bounds__(256) void k1_fused(
    const float* __restrict__ query, const float* __restrict__ entity,
    const float* __restrict__ conv_w, const float* __restrict__ e_w,
    const float* __restrict__ e_b, const float* __restrict__ q_w,
    const float* __restrict__ q_b, const float* __restrict__ k_w,
    const float* __restrict__ k_b, const float* __restrict__ wv,
    float* __restrict__ nq0, float* __restrict__ nq1, float* __restrict__ e_buf,
    float* __restrict__ qw_red, float* __restrict__ kw_red,
    float* __restrict__ qb_red, float* __restrict__ kb_red,
    float* __restrict__ Ewbuf) {
  __shared__ float smem[5504];
  int bid = blockIdx.x;
  if (bid < 192) {  // conv, split-K=2, direct conv_w
    int kz = bid / 96, t = bid % 96;
    int m0 = (t / 12) * 32, n0 = (t % 12) * 64;
    conv_core<0>(query, conv_w, kz ? nq1 : nq0, m0, n0, kz * 384, smem);
  } else if (bid < 240) {  // e = entity @ e_w^T + e_b
    int t = bid - 192;
    int m0 = (t / 6) * 32, n0 = (t % 6) * 64;
    gemm_plain<false, false>(entity, nullptr, nullptr, e_w, e_b, e_buf, 384,
                             m0, n0, 0, 768, smem);
  } else if (bid < 279) {  // fold attn_w into q_w/k_w (+ biases)
    int W = (bid - 240) * 4 + (threadIdx.x >> 6);
    int lane = threadIdx.x & 63;
    if (W < 72) {
      int h = W / 12, ib = W % 12, i = ib * 64 + lane;
      float s = 0.f;
#pragma unroll 8
      for (int d = 0; d < 64; ++d) s += q_w[(h * 64 + d) * 768 + i] * wv[d];
      qw_red[h * 768 + i] = s;
    } else if (W < 144) {
      int r = W - 72;
      int h = r / 12, ib = r % 12, i = ib * 64 + lane;
      float s = 0.f;
#pragma unroll 8
      for (int d = 0; d < 64; ++d) s += k_w[(h * 64 + d) * 768 + i] * wv[64 + d];
      kw_red[h * 768 + i] = s;
    } else if (W < 156) {
      int r = W - 144;
      float s;
      if (r < 6) {
        s = wsum(q_b[r * 64 + lane] * wv[lane]);
        if (lane == 0) qb_red[r] = s;
      } else {
        s = wsum(k_b[(r - 6) * 64 + lane] * wv[64 + lane]);
        if (lane == 0) kb_red[r - 6] = s;
      }
    }
  } else {  // Ew[t,b,cb] = entity[t,b,cb*64:] . wv[128:192]
    int row = (bid - 279) * 4 + (threadIdx.x >> 6);  // 0..255 = t*2+b
    int lane = threadIdx.x & 63;
    const float* erow = entity + (size_t)row * 768;
    float wvl = wv[128 + lane];
#pragma unroll
    for (int cb = 0; cb < 12; ++cb) {
      float s = wsum(erow[cb * 64 + lane] * wvl);
      if (lane == 0) Ewbuf[row * 12 + cb] = s;  // row*12 = t*24 + b*12
    }
  }
}

// =============== K2: v-gemm | A-dots | Bk-dots ===============
__global__ __launch_bounds__(256) void k2_fused(
    const float* __restrict__ nq0, const float* __restrict__ nq1,
    const float* __restrict__ conv_b, const float* __restrict__ v_w,
    const float* __restrict__ v_b, const float* __restrict__ e_buf,
    const float* __restrict__ qw_red, const float* __restrict__ kw_red,
    const float* __restrict__ qb_red, const float* __restrict__ kb_red,
    const float* __restrict__ wv, float* __restrict__ v_buf,
    float* __restrict__ Abuf, float* __restrict__ Bkbuf) {
  __shared__ float smem[3328];
  int bid = blockIdx.x;
  if (bid < 48) {  // v = (nq0+nq1+conv_b) @ v_w^T + v_b
    int m0 = (bid / 6) * 32, n0 = (bid % 6) * 64;
    gemm_plain<true, false>(nq0, nq1, conv_b, v_w, v_b, v_buf, 384,
                            m0, n0, 0, 768, smem);
    return;
  }
  int W = (bid - 48) * 4 + (threadIdx.x >> 6);  // 0..6143
  int lane = threadIdx.x & 63;
  if (W < 1536) {  // A q-part: m = b*12+h (h<6)
    int x = W & 127, q = W >> 7;  // q in [0,12)
    int b = q / 6, h = q % 6;
    const size_t row = (size_t)(x * 2 + b) * 768;
    const float* ww = qw_red + h * 768;
    float p = 0.f;
#pragma unroll
    for (int it = 0; it < 12; ++it) {
      int i = it * 64 + lane;
      p += (nq0[row + i] + nq1[row + i] + conv_b[i]) * ww[i];
    }
    float s = wsum(p) + qb_red[h];
    if (lane == 0) Abuf[(b * 12 + h) * 128 + x] = s;
  } else if (W < 3072) {  // A e-part: m = b*12+6+he
    int r = W - 1536;
    int x = r & 127, q = r >> 7;
    int b = q / 6, he = q % 6;
    float s = wsum(e_buf[(size_t)(x * 2 + b) * 384 + he * 64 + lane] * wv[lane]);
    if (lane == 0) Abuf[(b * 12 + 6 + he) * 128 + x] = s;
  } else if (W < 4608) {  // Bk q-part
    int r = W - 3072;
    int l = r & 127, q = r >> 7;
    int b = q / 6, h = q % 6;
    const size_t row = (size_t)(l * 2 + b) * 768;
    const float* ww = kw_red + h * 768;
    float p = 0.f;
#pragma unroll
    for (int it = 0; it < 12; ++it) {
      int i = it * 64 + lane;
      p += (nq0[row + i] + nq1[row + i] + conv_b[i]) * ww[i];
    }
    float s = wsum(p) + kb_red[h];
    if (lane == 0) Bkbuf[(b * 12 + h) * 128 + l] = s;
  } else {  // Bk e-part
    int r = W - 4608;
    int l = r & 127, q = r >> 7;
    int b = q / 6, he = q % 6;
    float s = wsum(e_buf[(size_t)(l * 2 + b) * 384 + he * 64 + lane] * wv[64 + lane]);
    if (lane == 0) Bkbuf[(b * 12 + 6 + he) * 128 + l] = s;
  }
}

// =============== K3: scores + leaky_relu + softmax + PV ===============
__global__ __launch_bounds__(128) void attn_kernel(
    const float* __restrict__ Abuf, const float* __restrict__ Bkbuf,
    const float* __restrict__ Ewbuf, const float* __restrict__ attn_b,
    const float* __restrict__ v_buf, const float* __restrict__ e_buf,
    float* __restrict__ a_out) {
  int bh = blockIdx.x >> 7, i2 = blockIdx.x & 127;
  int tid = threadIdx.x;
  int j = tid;
  int G = bh * 16384 + i2 * 128 + j;
  int mq = G % 24, xq = (G / 24) >> 7;
  int mk = (bh * 128 + i2) % 24;
  int cb = G % 12, gb = G / 12;
  int be = gb & 1, ij = gb >> 1, ie = ij >> 7, je = ij & 127;
  float s = Abuf[mq * 128 + xq] + Bkbuf[mk * 128 + j] + Ewbuf[ie * 24 + be * 12 + cb] -
            Ewbuf[je * 24 + be * 12 + cb] + attn_b[0];
  s = s >= 0.f ? s : 0.01f * s;

  __shared__ float ps[128];
  __shared__ float red[4];
  int lane = tid & 63, wid = tid >> 6;
  float mv = s;
#pragma unroll
  for (int off = 32; off; off >>= 1) mv = fmaxf(mv, __shfl_xor(mv, off, 64));
  if (lane == 0) red[wid] = mv;
  __syncthreads();
  float gmax = fmaxf(red[0], red[1]);
  float ex = expf(s - gmax);
  float sv = wsum(ex);
  if (lane == 0) red[2 + wid] = sv;
  __syncthreads();
  float gsum = red[2] + red[3];
  ps[tid] = ex / gsum;
  __syncthreads();

  int d = tid & 63, half = tid >> 6;
  int b = bh / 12, h = bh % 12;
  const float* src = (h < 6) ? (v_buf + h * 64) : (e_buf + (h - 6) * 64);
  float acc = 0.f;
#pragma unroll 4
  for (int jj = 0; jj < 64; ++jj) {
    int jx = half * 64 + jj;
    acc += ps[jx] * src[(size_t)(jx * 2 + b) * 384 + d];
  }
  __shared__ float pv[2][64];
  pv[half][d] = acc;
  __syncthreads();
  if (tid < 64) {
    a_out[(size_t)(i2 * 2 + b) * 768 + h * 64 + tid] = pv[0][tid] + pv[1][tid];
  }
}

// =============== K4: deconv (split2, direct deconv_w) -> y0/y1 partials ===============
__global__ __launch_bounds__(256) void k4_deconv(const float* __restrict__ a_buf,
                                                 const float* __restrict__ deconv_w,
                                                 float* __restrict__ y0,
                                                 float* __restrict__ y1) {
  __shared__ float smem[5504];
  int bid = blockIdx.x;
  int kz = bid / 96, t = bid % 96;
  int m0 = (t / 12) * 32, n0 = (t % 12) * 64;
  conv_core<1>(a_buf, deconv_w, kz ? y1 : y0, m0, n0, kz * 384, smem);
}

// =============== K5: out = (y0+y1+deconv_b) @ out_w^T + out_b (split2, atomic) ===============
__global__ __launch_bounds__(256) void k5_out(const float* __restrict__ y0,
                                              const float* __restrict__ y1,
                                              const float* __restrict__ deconv_b,
                                              const float* __restrict__ out_w,
                                              const float* __restrict__ out_b,
                                              float* __restrict__ dout) {
  __shared__ float smem[3328];
  int bid = blockIdx.x;
  int kz = bid / 96, t = bid % 96;
  int m0 = (t / 12) * 32, n0 = (t % 12) * 64;
  gemm_plain<true, true>(y0, y1, deconv_b, out_w, kz == 0 ? out_b : nullptr,
                         dout, 768, m0, n0, kz * 384, 384, smem);
}

extern "C" void kernel_launch(void* const* d_in, const int* in_sizes, int n_in,
                              void* d_out, int out_size, void* d_ws, size_t ws_size,
                              hipStream_t stream) {
  const float* query    = (const float*)d_in[0];
  const float* entity   = (const float*)d_in[1];
  const float* conv_w   = (const float*)d_in[2];
  const float* conv_b   = (const float*)d_in[3];
  const float* q_w      = (const float*)d_in[4];
  const float* q_b      = (const float*)d_in[5];
  const float* k_w      = (const float*)d_in[6];
  const float* k_b      = (const float*)d_in[7];
  const float* v_w      = (const float*)d_in[8];
  const float* v_b      = (const float*)d_in[9];
  const float* e_w      = (const float*)d_in[10];
  const float* e_b      = (const float*)d_in[11];
  const float* attn_w   = (const float*)d_in[12];
  const float* attn_b   = (const float*)d_in[13];
  const float* deconv_w = (const float*)d_in[14];
  const float* deconv_b = (const float*)d_in[15];
  const float* out_w    = (const float*)d_in[16];
  const float* out_b    = (const float*)d_in[17];

  float* ws     = (float*)d_ws;
  float* nq0    = ws;                  // 196608
  float* nq1    = nq0 + 196608;
  float* e_buf  = nq1 + 196608;        // 98304
  float* v_buf  = e_buf + 98304;       // 98304
  float* qw_red = v_buf + 98304;       // 4608
  float* kw_red = qw_red + 4608;       // 4608
  float* qb_red = kw_red + 4608;       // 8
  float* kb_red = qb_red + 8;          // 8
  float* Abuf   = kb_red + 8;          // 3072
  float* Bkbuf  = Abuf + 3072;         // 3072
  float* Ewbuf  = Bkbuf + 3072;        // 3072
  float* a_buf  = Ewbuf + 3072;        // 196608
  float* y0     = a_buf + 196608;      // 196608
  float* y1     = y0 + 196608;         // 196608

  float* dout = (float*)d_out;

  k1_fused<<<343, 256, 0, stream>>>(query, entity, conv_w, e_w, e_b, q_w, q_b,
                                    k_w, k_b, attn_w, nq0, nq1, e_buf, qw_red,
                                    kw_red, qb_red, kb_red, Ewbuf);
  k2_fused<<<1584, 256, 0, stream>>>(nq0, nq1, conv_b, v_w, v_b, e_buf, qw_red,
                                     kw_red, qb_red, kb_red, attn_w, v_buf,
                                     Abuf, Bkbuf);
  attn_kernel<<<3072, 128, 0, stream>>>(Abuf, Bkbuf, Ewbuf, attn_b, v_buf,
                                        e_buf, a_buf);
  k4_deconv<<<192, 256, 0, stream>>>(a_buf, deconv_w, y0, y1);
  k5_out<<<192, 256, 0, stream>>>(y0, y1, deconv_b, out_w, out_b, dout);
}